// Round 2
// baseline (1640.423 us; speedup 1.0000x reference)
//
#include <hip/hip_runtime.h>
#include <cstddef>
#include <cstdint>
#include <cmath>

#define NPIX     12288
#define NBUCKETS 32
#define IN_DIM   32
#define PROJ_IN  1056
#define PROJ_OUT 256
#define OUT_DIM  128
#define LN_EPS   1e-5f
#define NBATCH   4

#define ROWS   (NBATCH * NPIX)        // 49152
#define GCELLS (ROWS * NBUCKETS)      // 1,572,864

#define BM 64
#define BK 32

// ---------------------------------------------------------------------------
// Phase 1: scatter-add. 8 threads per point; each thread handles one float4
// of the 32-feature row (perfectly coalesced 128B per 8 lanes), 4 atomics.
// ---------------------------------------------------------------------------
__global__ __launch_bounds__(256)
void scatter_kernel(const float* __restrict__ feats,
                    const int*   __restrict__ bidx,
                    const int*   __restrict__ pix,
                    const int*   __restrict__ bucket,
                    float* __restrict__ sums,
                    float* __restrict__ counts,
                    int N)
{
    int gid = blockIdx.x * 256 + threadIdx.x;
    int p   = gid >> 3;
    if (p >= N) return;
    int c4  = gid & 7;
    int flat = bidx[p] * (NPIX * NBUCKETS) + pix[p] * NBUCKETS + bucket[p];
    float4 v = reinterpret_cast<const float4*>(feats)[(size_t)p * 8 + c4];
    float* dst = sums + (size_t)flat * IN_DIM + c4 * 4;
    atomicAdd(dst + 0, v.x);
    atomicAdd(dst + 1, v.y);
    atomicAdd(dst + 2, v.z);
    atomicAdd(dst + 3, v.w);
    if (c4 == 0) atomicAdd(counts + flat, 1.0f);
}

// ---------------------------------------------------------------------------
// Fallback: write zeros to d_out (used only if ws_size is too small; fails
// validation gracefully instead of faulting the GPU with OOB atomics).
// ---------------------------------------------------------------------------
__global__ void zero_out_kernel(float* __restrict__ out, size_t n)
{
    size_t i = (size_t)blockIdx.x * blockDim.x + threadIdx.x;
    if (i < n) out[i] = 0.f;
}

// ---------------------------------------------------------------------------
// Phase 2: fused mean + GEMM1(1056->256) + LayerNorm + SiLU + GEMM2(256->128).
// Block = 256 threads, 64 rows. sums is (49152 x 1024) row-major == aggregated.
// K-step s<32 covers bucket b==s (k = s*32 + kk), step 32 is the has_obs tail.
// ---------------------------------------------------------------------------
__global__ __launch_bounds__(256, 3)
void fused_mlp_kernel(const float* __restrict__ sums,
                      const float* __restrict__ counts,
                      const float* __restrict__ W1,   // 1056 x 256
                      const float* __restrict__ b1,   // 256
                      const float* __restrict__ ln_g, // 256
                      const float* __restrict__ ln_b, // 256
                      const float* __restrict__ W2,   // 256 x 128
                      const float* __restrict__ b2,   // 128
                      float* __restrict__ out)        // 49152 x 128
{
    // LDS: Bs[32][256] (32KB) | As[32][64] (8KB) | cnts[64][32] (8KB) = 48KB
    // Epilogue aliases h_s[32][256] over Bs.
    __shared__ __align__(16) float smem[8192 + 2048 + 2048];
    float* Bs   = smem;
    float* As   = smem + 8192;
    float* cnts = smem + 8192 + 2048;
    float* h_s  = smem;

    const int t    = threadIdx.x;
    const int row0 = blockIdx.x * BM;
    const int tr   = t >> 5;     // 0..7 -> rows m0..m0+7
    const int tc   = t & 31;     // 0..31 -> cols c0..c0+7
    const int m0   = tr * 8;
    const int c0   = tc * 8;

    // counts tile: cnts[m][b] = counts[(row0+m)*32 + b]  (linear copy)
    {
        const float4* src = reinterpret_cast<const float4*>(counts + (size_t)row0 * NBUCKETS);
        float4* dst = reinterpret_cast<float4*>(cnts);
        dst[t]       = src[t];
        dst[t + 256] = src[t + 256];
    }
    __syncthreads();

    float acc[8][8];
#pragma unroll
    for (int i = 0; i < 8; ++i)
#pragma unroll
        for (int j = 0; j < 8; ++j) acc[i][j] = 0.f;

    const int ar = t >> 3;   // 0..31 (A-staging row; also handles ar+32)
    const int aq = t & 7;    // float4 slot within the 32-wide k chunk

    for (int s = 0; s < 33; ++s) {
        // stage B: 32 contiguous rows of W1 -> 32KB linear copy
        {
            const float4* src = reinterpret_cast<const float4*>(W1 + (size_t)s * BK * PROJ_OUT);
            float4* dst = reinterpret_cast<float4*>(Bs);
#pragma unroll
            for (int i = 0; i < 8; ++i) dst[t + i * 256] = src[t + i * 256];
        }
        // stage A transposed: As[kk][m]
        if (s < 32) {
#pragma unroll
            for (int h = 0; h < 2; ++h) {
                const int r = ar + h * 32;
                const float c = cnts[r * 32 + s];
                const float inv = (c > 0.f) ? (1.f / c) : 0.f;
                const float4 v = *reinterpret_cast<const float4*>(
                    &sums[(size_t)(row0 + r) * 1024 + s * 32 + aq * 4]);
                As[(aq * 4 + 0) * 64 + r] = v.x * inv;
                As[(aq * 4 + 1) * 64 + r] = v.y * inv;
                As[(aq * 4 + 2) * 64 + r] = v.z * inv;
                As[(aq * 4 + 3) * 64 + r] = v.w * inv;
            }
        } else {  // has_obs tail: k = 1024 + kk -> bucket kk
#pragma unroll
            for (int h = 0; h < 2; ++h) {
                const int r = ar + h * 32;
#pragma unroll
                for (int i = 0; i < 4; ++i) {
                    const int kk = aq * 4 + i;
                    As[kk * 64 + r] = (cnts[r * 32 + kk] > 0.f) ? 1.f : 0.f;
                }
            }
        }
        __syncthreads();

#pragma unroll 8
        for (int kk = 0; kk < BK; ++kk) {
            float a[8], b[8];
            *reinterpret_cast<float4*>(&a[0]) = *reinterpret_cast<const float4*>(&As[kk * 64 + m0]);
            *reinterpret_cast<float4*>(&a[4]) = *reinterpret_cast<const float4*>(&As[kk * 64 + m0 + 4]);
            *reinterpret_cast<float4*>(&b[0]) = *reinterpret_cast<const float4*>(&Bs[kk * 256 + c0]);
            *reinterpret_cast<float4*>(&b[4]) = *reinterpret_cast<const float4*>(&Bs[kk * 256 + c0 + 4]);
#pragma unroll
            for (int i = 0; i < 8; ++i)
#pragma unroll
                for (int j = 0; j < 8; ++j)
                    acc[i][j] = fmaf(a[i], b[j], acc[i][j]);
        }
        __syncthreads();
    }

    // ---- epilogue: two halves of 32 rows (h_s aliases Bs) ----
    float b1v[8];
    *reinterpret_cast<float4*>(&b1v[0]) = *reinterpret_cast<const float4*>(&b1[c0]);
    *reinterpret_cast<float4*>(&b1v[4]) = *reinterpret_cast<const float4*>(&b1[c0 + 4]);

    const int lane = t & 63;
    const int wv   = t >> 6;
    const float g0 = ln_g[lane], g1 = ln_g[lane + 64], g2 = ln_g[lane + 128], g3 = ln_g[lane + 192];
    const float e0 = ln_b[lane], e1 = ln_b[lane + 64], e2 = ln_b[lane + 128], e3 = ln_b[lane + 192];

    for (int half = 0; half < 2; ++half) {
        __syncthreads();
        if ((tr >> 2) == half) {
            const int mb = m0 - half * 32;
#pragma unroll
            for (int i = 0; i < 8; ++i) {
                float4 w0 = make_float4(acc[i][0] + b1v[0], acc[i][1] + b1v[1],
                                        acc[i][2] + b1v[2], acc[i][3] + b1v[3]);
                float4 w1 = make_float4(acc[i][4] + b1v[4], acc[i][5] + b1v[5],
                                        acc[i][6] + b1v[6], acc[i][7] + b1v[7]);
                *reinterpret_cast<float4*>(&h_s[(mb + i) * 256 + c0])     = w0;
                *reinterpret_cast<float4*>(&h_s[(mb + i) * 256 + c0 + 4]) = w1;
            }
        }
        __syncthreads();

        // LayerNorm + SiLU: each wave owns rows {wv, wv+4, ...}
        for (int r = wv; r < 32; r += 4) {
            float v0 = h_s[r * 256 + lane];
            float v1 = h_s[r * 256 + lane + 64];
            float v2 = h_s[r * 256 + lane + 128];
            float v3 = h_s[r * 256 + lane + 192];
            float sum = v0 + v1 + v2 + v3;
            float sq  = fmaf(v0, v0, fmaf(v1, v1, fmaf(v2, v2, v3 * v3)));
#pragma unroll
            for (int off = 32; off > 0; off >>= 1) {
                sum += __shfl_xor(sum, off);
                sq  += __shfl_xor(sq, off);
            }
            const float mu  = sum * (1.0f / 256.0f);
            const float var = sq * (1.0f / 256.0f) - mu * mu;
            const float rs  = rsqrtf(var + LN_EPS);
            v0 = fmaf((v0 - mu) * rs, g0, e0);
            v1 = fmaf((v1 - mu) * rs, g1, e1);
            v2 = fmaf((v2 - mu) * rs, g2, e2);
            v3 = fmaf((v3 - mu) * rs, g3, e3);
            v0 = v0 / (1.f + expf(-v0));
            v1 = v1 / (1.f + expf(-v1));
            v2 = v2 / (1.f + expf(-v2));
            v3 = v3 / (1.f + expf(-v3));
            h_s[r * 256 + lane]       = v0;
            h_s[r * 256 + lane + 64]  = v1;
            h_s[r * 256 + lane + 128] = v2;
            h_s[r * 256 + lane + 192] = v3;
        }
        __syncthreads();

        // GEMM2: (32 x 256) @ (256 x 128). thread: col c, 16 rows.
        {
            const int c  = t & 127;
            const int gg = t >> 7;   // 0..1
            float acc2[16];
#pragma unroll
            for (int i = 0; i < 16; ++i) acc2[i] = 0.f;
            for (int k = 0; k < 256; k += 4) {
                const float wa = W2[(k + 0) * 128 + c];
                const float wb = W2[(k + 1) * 128 + c];
                const float wc = W2[(k + 2) * 128 + c];
                const float wd = W2[(k + 3) * 128 + c];
#pragma unroll
                for (int i = 0; i < 16; ++i) {
                    const float4 h4 = *reinterpret_cast<const float4*>(&h_s[(gg * 16 + i) * 256 + k]);
                    acc2[i] = fmaf(h4.x, wa, acc2[i]);
                    acc2[i] = fmaf(h4.y, wb, acc2[i]);
                    acc2[i] = fmaf(h4.z, wc, acc2[i]);
                    acc2[i] = fmaf(h4.w, wd, acc2[i]);
                }
            }
            const float bias = b2[c];
#pragma unroll
            for (int i = 0; i < 16; ++i) {
                const int m = gg * 16 + i;
                out[(size_t)(row0 + half * 32 + m) * 128 + c] = acc2[i] + bias;
            }
        }
    }
}

// ---------------------------------------------------------------------------
extern "C" void kernel_launch(void* const* d_in, const int* in_sizes, int n_in,
                              void* d_out, int out_size, void* d_ws, size_t ws_size,
                              hipStream_t stream)
{
    const float* feats  = (const float*)d_in[0];
    const int*   bidx   = (const int*)d_in[1];
    const int*   pix    = (const int*)d_in[2];
    const int*   bucket = (const int*)d_in[3];
    // d_in[4] = nbatch scalar (== 4, hardcoded as NBATCH)
    const float* W1   = (const float*)d_in[5];
    const float* b1   = (const float*)d_in[6];
    const float* ln_g = (const float*)d_in[7];
    const float* ln_b = (const float*)d_in[8];
    const float* W2   = (const float*)d_in[9];
    const float* b2   = (const float*)d_in[10];
    float* out = (float*)d_out;

    const int N = in_sizes[1];   // 2,000,000

    const size_t ws_needed = (size_t)GCELLS * (IN_DIM + 1) * sizeof(float); // 207.6 MB
    if (ws_size < ws_needed) {
        // Workspace too small for the fp32 scatter grid. Fail validation
        // gracefully (zeros) instead of faulting the GPU with OOB atomics.
        size_t n = (size_t)out_size;
        zero_out_kernel<<<(unsigned)((n + 255) / 256), 256, 0, stream>>>(out, n);
        return;
    }

    float* sums   = (float*)d_ws;                       // GCELLS x 32
    float* counts = sums + (size_t)GCELLS * IN_DIM;     // GCELLS

    // zero sums + counts (ws is re-poisoned to 0xAA before every call)
    hipMemsetAsync(d_ws, 0, ws_needed, stream);

    const int sgrid = (N * 8 + 255) / 256;
    scatter_kernel<<<sgrid, 256, 0, stream>>>(feats, bidx, pix, bucket, sums, counts, N);

    fused_mlp_kernel<<<ROWS / BM, 256, 0, stream>>>(sums, counts, W1, b1, ln_g, ln_b,
                                                    W2, b2, out);
}

// Round 3
// 1048.757 us; speedup vs baseline: 1.5642x; 1.5642x over previous
//
#include <hip/hip_runtime.h>
#include <cstddef>
#include <cstdint>
#include <cmath>

#define NPIX     12288
#define NBUCKETS 32
#define IN_DIM   32
#define PROJ_IN  1056
#define PROJ_OUT 256
#define OUT_DIM  128
#define LN_EPS   1e-5f
#define NBATCH   4

#define ROWS   (NBATCH * NPIX)        // 49152
#define GCELLS (ROWS * NBUCKETS)      // 1,572,864

#define BM 64
#define BK 32

#define SCAN_CHUNK 2048
#define NBLK_SCAN  (GCELLS / SCAN_CHUNK)   // 768

// ---------------------------------------------------------------------------
// K1: flat index + histogram (counts into `cnt`, which is the cursor array).
// ---------------------------------------------------------------------------
__global__ __launch_bounds__(256)
void flat_hist_kernel(const int* __restrict__ bidx, const int* __restrict__ pix,
                      const int* __restrict__ bucket, int* __restrict__ flat,
                      int* __restrict__ cnt, int N)
{
    int p = blockIdx.x * 256 + threadIdx.x;
    if (p >= N) return;
    int f = bidx[p] * (NPIX * NBUCKETS) + pix[p] * NBUCKETS + bucket[p];
    flat[p] = f;
    atomicAdd(&cnt[f], 1);
}

// ---------------------------------------------------------------------------
// K2a: per-chunk (2048) reduction of counts -> partials[NBLK_SCAN]
// ---------------------------------------------------------------------------
__global__ __launch_bounds__(256)
void scan_reduce_kernel(const int* __restrict__ cnt, int* __restrict__ partials)
{
    __shared__ int wsum[4];
    const int b = blockIdx.x, t = threadIdx.x;
    const int4* src = reinterpret_cast<const int4*>(cnt + (size_t)b * SCAN_CHUNK);
    int4 v0 = src[t * 2], v1 = src[t * 2 + 1];
    int s = v0.x + v0.y + v0.z + v0.w + v1.x + v1.y + v1.z + v1.w;
#pragma unroll
    for (int off = 32; off; off >>= 1) s += __shfl_xor(s, off);
    if ((t & 63) == 0) wsum[t >> 6] = s;
    __syncthreads();
    if (t == 0) partials[b] = wsum[0] + wsum[1] + wsum[2] + wsum[3];
}

// ---------------------------------------------------------------------------
// K2b: exclusive scan of the 768 partials in place. One wave (64 thr x 12).
// ---------------------------------------------------------------------------
__global__ void scan_mid_kernel(int* __restrict__ partials)
{
    const int t = threadIdx.x;   // 0..63
    int v[12]; int s = 0;
#pragma unroll
    for (int i = 0; i < 12; ++i) { v[i] = partials[t * 12 + i]; s += v[i]; }
    int inc = s;
#pragma unroll
    for (int d = 1; d < 64; d <<= 1) { int o = __shfl_up(inc, d); if (t >= d) inc += o; }
    int base = inc - s;
#pragma unroll
    for (int i = 0; i < 12; ++i) { int x = v[i]; partials[t * 12 + i] = base; base += x; }
}

// ---------------------------------------------------------------------------
// K2c: write exclusive offsets; also initialize cursor = offs (for reorder).
// ---------------------------------------------------------------------------
__global__ __launch_bounds__(256)
void scan_write_kernel(const int* __restrict__ partials,
                       int* __restrict__ offs, int* __restrict__ cursor)
{
    __shared__ int wbase[4];
    const int b = blockIdx.x, t = threadIdx.x;
    const int lane = t & 63, w = t >> 6;
    const int4* src = reinterpret_cast<const int4*>(cursor + (size_t)b * SCAN_CHUNK);
    int4 v0 = src[t * 2], v1 = src[t * 2 + 1];
    int a[8] = { v0.x, v0.y, v0.z, v0.w, v1.x, v1.y, v1.z, v1.w };
    int s = 0;
#pragma unroll
    for (int i = 0; i < 8; ++i) s += a[i];
    int inc = s;
#pragma unroll
    for (int d = 1; d < 64; d <<= 1) { int o = __shfl_up(inc, d); if (lane >= d) inc += o; }
    if (lane == 63) wbase[w] = inc;
    __syncthreads();
    int wb = 0;
    for (int i = 0; i < w; ++i) wb += wbase[i];
    int base = partials[b] + wb + (inc - s);
    const int idx0 = b * SCAN_CHUNK + t * 8;
#pragma unroll
    for (int i = 0; i < 8; ++i) { offs[idx0 + i] = base; cursor[idx0 + i] = base; base += a[i]; }
    if (b == (int)gridDim.x - 1 && t == 255) offs[GCELLS] = base;
}

// ---------------------------------------------------------------------------
// K3: reorder point indices into cell-grouped order[].
// ---------------------------------------------------------------------------
__global__ __launch_bounds__(256)
void reorder_kernel(const int* __restrict__ flat, int* __restrict__ cursor,
                    int* __restrict__ order, int N)
{
    int p = blockIdx.x * 256 + threadIdx.x;
    if (p >= N) return;
    int f = flat[p];
    int slot = atomicAdd(&cursor[f], 1);
    order[slot] = p;
}

// ---------------------------------------------------------------------------
// Fallback: write zeros to d_out if ws is too small (graceful fail).
// ---------------------------------------------------------------------------
__global__ void zero_out_kernel(float* __restrict__ out, size_t n)
{
    size_t i = (size_t)blockIdx.x * blockDim.x + threadIdx.x;
    if (i < n) out[i] = 0.f;
}

// ---------------------------------------------------------------------------
// Phase 2: fused gather-mean + GEMM1(1056->256) + LN + SiLU + GEMM2(256->128).
// Block = 256 threads, 64 rows. K-step s<32 covers bucket b==s, step 32 is the
// has_obs tail. A-operand is gathered directly from feats via order/offs.
// ---------------------------------------------------------------------------
__global__ __launch_bounds__(256, 3)
void fused_mlp_kernel(const float* __restrict__ feats,
                      const int*   __restrict__ order_g,
                      const int*   __restrict__ offs_g,
                      const float* __restrict__ W1,   // 1056 x 256
                      const float* __restrict__ b1,   // 256
                      const float* __restrict__ ln_g, // 256
                      const float* __restrict__ ln_b, // 256
                      const float* __restrict__ W2,   // 256 x 128
                      const float* __restrict__ b2,   // 128
                      float* __restrict__ out)        // 49152 x 128
{
    // LDS: Bs[32][256] (32KB) | As[32][64] (8KB) | offsT[2052] (8.2KB)
    // Epilogue aliases h_s[32][256] over Bs.
    __shared__ __align__(16) float smem[8192 + 2048 + 2052];
    float* Bs   = smem;
    float* As   = smem + 8192;
    int*   offsT = reinterpret_cast<int*>(smem + 8192 + 2048);
    float* h_s  = smem;

    const int t    = threadIdx.x;
    const int row0 = blockIdx.x * BM;
    const int tr   = t >> 5;     // 0..7
    const int tc   = t & 31;     // 0..31
    const int m0   = tr * 8;
    const int c0   = tc * 8;

    // stage offsets tile: cells [row0*32, row0*32+2048], 2049 ints
    {
        const int4* s4 = reinterpret_cast<const int4*>(offs_g + (size_t)row0 * NBUCKETS);
        int4* d4 = reinterpret_cast<int4*>(offsT);
        d4[t]       = s4[t];
        d4[t + 256] = s4[t + 256];
        if (t == 0) offsT[2048] = offs_g[(size_t)row0 * NBUCKETS + 2048];
    }
    __syncthreads();

    float acc[8][8];
#pragma unroll
    for (int i = 0; i < 8; ++i)
#pragma unroll
        for (int j = 0; j < 8; ++j) acc[i][j] = 0.f;

    const int ar = t >> 3;   // 0..31 (A-staging row; also handles ar+32)
    const int aq = t & 7;    // float4 slot within the 32-wide k chunk
    const float4* feats4 = reinterpret_cast<const float4*>(feats);

    for (int s = 0; s < 33; ++s) {
        // stage B: 32 contiguous rows of W1 -> 32KB linear copy
        {
            const float4* src = reinterpret_cast<const float4*>(W1 + (size_t)s * BK * PROJ_OUT);
            float4* dst = reinterpret_cast<float4*>(Bs);
#pragma unroll
            for (int i = 0; i < 8; ++i) dst[t + i * 256] = src[t + i * 256];
        }
        // stage A transposed: As[kk][m] via gather-mean
        if (s < 32) {
#pragma unroll
            for (int h = 0; h < 2; ++h) {
                const int r = ar + h * 32;
                const int cell = r * NBUCKETS + s;
                const int start = offsT[cell], end = offsT[cell + 1];
                float4 a4 = make_float4(0.f, 0.f, 0.f, 0.f);
                for (int j = start; j < end; ++j) {
                    const int idx = order_g[j];
                    const float4 v = feats4[(size_t)idx * 8 + aq];
                    a4.x += v.x; a4.y += v.y; a4.z += v.z; a4.w += v.w;
                }
                const int cnt = end - start;
                const float inv = cnt ? 1.0f / (float)cnt : 0.f;
                As[(aq * 4 + 0) * 64 + r] = a4.x * inv;
                As[(aq * 4 + 1) * 64 + r] = a4.y * inv;
                As[(aq * 4 + 2) * 64 + r] = a4.z * inv;
                As[(aq * 4 + 3) * 64 + r] = a4.w * inv;
            }
        } else {  // has_obs tail: k = 1024 + kk -> bucket kk
#pragma unroll
            for (int h = 0; h < 2; ++h) {
                const int r = ar + h * 32;
#pragma unroll
                for (int i = 0; i < 4; ++i) {
                    const int kk = aq * 4 + i;
                    As[kk * 64 + r] = (offsT[r * NBUCKETS + kk + 1] > offsT[r * NBUCKETS + kk]) ? 1.f : 0.f;
                }
            }
        }
        __syncthreads();

#pragma unroll 8
        for (int kk = 0; kk < BK; ++kk) {
            float a[8], b[8];
            *reinterpret_cast<float4*>(&a[0]) = *reinterpret_cast<const float4*>(&As[kk * 64 + m0]);
            *reinterpret_cast<float4*>(&a[4]) = *reinterpret_cast<const float4*>(&As[kk * 64 + m0 + 4]);
            *reinterpret_cast<float4*>(&b[0]) = *reinterpret_cast<const float4*>(&Bs[kk * 256 + c0]);
            *reinterpret_cast<float4*>(&b[4]) = *reinterpret_cast<const float4*>(&Bs[kk * 256 + c0 + 4]);
#pragma unroll
            for (int i = 0; i < 8; ++i)
#pragma unroll
                for (int j = 0; j < 8; ++j)
                    acc[i][j] = fmaf(a[i], b[j], acc[i][j]);
        }
        __syncthreads();
    }

    // ---- epilogue: two halves of 32 rows (h_s aliases Bs) ----
    float b1v[8];
    *reinterpret_cast<float4*>(&b1v[0]) = *reinterpret_cast<const float4*>(&b1[c0]);
    *reinterpret_cast<float4*>(&b1v[4]) = *reinterpret_cast<const float4*>(&b1[c0 + 4]);

    const int lane = t & 63;
    const int wv   = t >> 6;
    const float g0 = ln_g[lane], g1 = ln_g[lane + 64], g2 = ln_g[lane + 128], g3 = ln_g[lane + 192];
    const float e0 = ln_b[lane], e1 = ln_b[lane + 64], e2 = ln_b[lane + 128], e3 = ln_b[lane + 192];

    for (int half = 0; half < 2; ++half) {
        __syncthreads();
        if ((tr >> 2) == half) {
            const int mb = m0 - half * 32;
#pragma unroll
            for (int i = 0; i < 8; ++i) {
                float4 w0 = make_float4(acc[i][0] + b1v[0], acc[i][1] + b1v[1],
                                        acc[i][2] + b1v[2], acc[i][3] + b1v[3]);
                float4 w1 = make_float4(acc[i][4] + b1v[4], acc[i][5] + b1v[5],
                                        acc[i][6] + b1v[6], acc[i][7] + b1v[7]);
                *reinterpret_cast<float4*>(&h_s[(mb + i) * 256 + c0])     = w0;
                *reinterpret_cast<float4*>(&h_s[(mb + i) * 256 + c0 + 4]) = w1;
            }
        }
        __syncthreads();

        // LayerNorm + SiLU: each wave owns rows {wv, wv+4, ...}
        for (int r = wv; r < 32; r += 4) {
            float v0 = h_s[r * 256 + lane];
            float v1 = h_s[r * 256 + lane + 64];
            float v2 = h_s[r * 256 + lane + 128];
            float v3 = h_s[r * 256 + lane + 192];
            float sum = v0 + v1 + v2 + v3;
            float sq  = fmaf(v0, v0, fmaf(v1, v1, fmaf(v2, v2, v3 * v3)));
#pragma unroll
            for (int off = 32; off > 0; off >>= 1) {
                sum += __shfl_xor(sum, off);
                sq  += __shfl_xor(sq, off);
            }
            const float mu  = sum * (1.0f / 256.0f);
            const float var = sq * (1.0f / 256.0f) - mu * mu;
            const float rs  = rsqrtf(var + LN_EPS);
            v0 = fmaf((v0 - mu) * rs, g0, e0);
            v1 = fmaf((v1 - mu) * rs, g1, e1);
            v2 = fmaf((v2 - mu) * rs, g2, e2);
            v3 = fmaf((v3 - mu) * rs, g3, e3);
            v0 = v0 / (1.f + expf(-v0));
            v1 = v1 / (1.f + expf(-v1));
            v2 = v2 / (1.f + expf(-v2));
            v3 = v3 / (1.f + expf(-v3));
            h_s[r * 256 + lane]       = v0;
            h_s[r * 256 + lane + 64]  = v1;
            h_s[r * 256 + lane + 128] = v2;
            h_s[r * 256 + lane + 192] = v3;
        }
        __syncthreads();

        // GEMM2: (32 x 256) @ (256 x 128). thread: col c, 16 rows.
        {
            const int c  = t & 127;
            const int gg = t >> 7;   // 0..1
            float acc2[16];
#pragma unroll
            for (int i = 0; i < 16; ++i) acc2[i] = 0.f;
            for (int k = 0; k < 256; k += 4) {
                const float wa = W2[(k + 0) * 128 + c];
                const float wb = W2[(k + 1) * 128 + c];
                const float wc = W2[(k + 2) * 128 + c];
                const float wd = W2[(k + 3) * 128 + c];
#pragma unroll
                for (int i = 0; i < 16; ++i) {
                    const float4 h4 = *reinterpret_cast<const float4*>(&h_s[(gg * 16 + i) * 256 + k]);
                    acc2[i] = fmaf(h4.x, wa, acc2[i]);
                    acc2[i] = fmaf(h4.y, wb, acc2[i]);
                    acc2[i] = fmaf(h4.z, wc, acc2[i]);
                    acc2[i] = fmaf(h4.w, wd, acc2[i]);
                }
            }
            const float bias = b2[c];
#pragma unroll
            for (int i = 0; i < 16; ++i) {
                const int m = gg * 16 + i;
                out[(size_t)(row0 + half * 32 + m) * 128 + c] = acc2[i] + bias;
            }
        }
    }
}

// ---------------------------------------------------------------------------
extern "C" void kernel_launch(void* const* d_in, const int* in_sizes, int n_in,
                              void* d_out, int out_size, void* d_ws, size_t ws_size,
                              hipStream_t stream)
{
    const float* feats  = (const float*)d_in[0];
    const int*   bidx   = (const int*)d_in[1];
    const int*   pix    = (const int*)d_in[2];
    const int*   bucket = (const int*)d_in[3];
    // d_in[4] = nbatch scalar (== 4, hardcoded as NBATCH)
    const float* W1   = (const float*)d_in[5];
    const float* b1   = (const float*)d_in[6];
    const float* ln_g = (const float*)d_in[7];
    const float* ln_b = (const float*)d_in[8];
    const float* W2   = (const float*)d_in[9];
    const float* b2   = (const float*)d_in[10];
    float* out = (float*)d_out;

    const int N = in_sizes[1];   // 2,000,000

    // workspace layout (ints)
    int* flat     = (int*)d_ws;               // N
    int* order    = flat + N;                 // N
    int* cursor   = order + N;                // GCELLS (histogram counts, then cursors)
    int* offs     = cursor + GCELLS;          // GCELLS + 1
    int* partials = offs + GCELLS + 1;        // NBLK_SCAN

    const size_t ws_needed = ((size_t)2 * N + 2 * GCELLS + 1 + NBLK_SCAN) * sizeof(int);
    if (ws_size < ws_needed) {
        size_t n = (size_t)out_size;
        zero_out_kernel<<<(unsigned)((n + 255) / 256), 256, 0, stream>>>(out, n);
        return;
    }

    hipMemsetAsync(cursor, 0, (size_t)GCELLS * sizeof(int), stream);

    const int pgrid = (N + 255) / 256;
    flat_hist_kernel<<<pgrid, 256, 0, stream>>>(bidx, pix, bucket, flat, cursor, N);
    scan_reduce_kernel<<<NBLK_SCAN, 256, 0, stream>>>(cursor, partials);
    scan_mid_kernel<<<1, 64, 0, stream>>>(partials);
    scan_write_kernel<<<NBLK_SCAN, 256, 0, stream>>>(partials, offs, cursor);
    reorder_kernel<<<pgrid, 256, 0, stream>>>(flat, cursor, order, N);

    fused_mlp_kernel<<<ROWS / BM, 256, 0, stream>>>(feats, order, offs, W1, b1,
                                                    ln_g, ln_b, W2, b2, out);
}